// Round 1
// baseline (567.676 us; speedup 1.0000x reference)
//
#include <hip/hip_runtime.h>
#include <hip/hip_bf16.h>
#include <math.h>

#define LOG2E_F 1.4426950408889634f

static constexpr int BT = 64;
static constexpr int DK = 64;
static constexpr int DV = 64;
static constexpr float SCALE = 0.125f;

__device__ __forceinline__ float logsig_log2e(float x){
    float l = (x >= 0.f) ? (-log1pf(expf(-x))) : (x - log1pf(expf(x)));
    return l * LOG2E_F;
}

// ---------------- Pass 1: inter-chunk state recurrence ----------------
__global__ __launch_bounds__(256) void pass1_kernel(
    const float* __restrict__ kg, const float* __restrict__ vg,
    const float* __restrict__ ig, const float* __restrict__ fg,
    float* __restrict__ Cws, float* __restrict__ nws, float* __restrict__ mws,
    int T, int NT)
{
    const int vb  = blockIdx.x;
    const int s   = blockIdx.y;
    const int tid = threadIdx.x;
    const int lane = tid & 63;

    __shared__ float kbuf[BT][DK];
    __shared__ float vbuf[BT][16];
    __shared__ float gscale[BT];
    __shared__ float sh_dec;

    const float* kseq = kg + (size_t)s * T * DK;
    const float* vseq = vg + (size_t)s * T * DV + vb * 16;
    const float* iseq = ig + (size_t)s * T;
    const float* fseq = fg + (size_t)s * T;

    const int kk  = tid >> 2;
    const int vv0 = (tid & 3) * 4;

    float Creg[4] = {0.f, 0.f, 0.f, 0.f};
    float nreg = 0.f;
    float m = 0.f;

    for (int t = 0; t < NT; ++t){
        {
            size_t off = (((size_t)(s * NT + t)) * DK + kk) * DV + vb * 16 + vv0;
            *(float4*)(Cws + off) = make_float4(Creg[0], Creg[1], Creg[2], Creg[3]);
            if (vb == 0 && tid < 64) nws[((size_t)(s * NT + t)) * DK + lane] = nreg;
            if (vb == 0 && tid == 0) mws[s * NT + t] = m;
        }
        if (tid < 64){
            float b = logsig_log2e(fseq[t * BT + lane]);
            #pragma unroll
            for (int off = 1; off < 64; off <<= 1){
                float y = __shfl_up(b, off);
                if (lane >= off) b += y;
            }
            float f_last = __shfl(b, 63);
            float g = iseq[t * BT + lane] * LOG2E_F + f_last - b;
            float gm = g;
            #pragma unroll
            for (int off = 32; off > 0; off >>= 1) gm = fmaxf(gm, __shfl_xor(gm, off));
            float m_next = fmaxf(f_last + m, gm);
            gscale[lane] = exp2f(g - m_next);
            if (tid == 0) sh_dec = exp2f(f_last + m - m_next);
            m = m_next;
        }
        {
            const float* kc = kseq + (size_t)t * BT * DK;
            #pragma unroll
            for (int base = 0; base < BT * DK; base += 1024){
                int idx = base + tid * 4;
                float4 t4 = *(const float4*)(kc + idx);
                int r = idx >> 6, c = idx & 63;
                kbuf[r][c] = t4.x; kbuf[r][c+1] = t4.y; kbuf[r][c+2] = t4.z; kbuf[r][c+3] = t4.w;
            }
            const float* vc = vseq + (size_t)t * BT * DV;
            int idx = tid * 4;
            int r = idx >> 4, j = idx & 15;
            float4 t4 = *(const float4*)(vc + (size_t)r * DV + j);
            vbuf[r][j] = t4.x; vbuf[r][j+1] = t4.y; vbuf[r][j+2] = t4.z; vbuf[r][j+3] = t4.w;
        }
        __syncthreads();
        {
            float dec = sh_dec;
            #pragma unroll
            for (int j = 0; j < 4; ++j) Creg[j] *= dec;
            for (int c = 0; c < BT; ++c){
                float kd = kbuf[c][kk] * gscale[c];
                #pragma unroll
                for (int j = 0; j < 4; ++j)
                    Creg[j] = fmaf(kd, vbuf[c][vv0 + j], Creg[j]);
            }
            if (vb == 0 && tid < 64){
                float acc = 0.f;
                for (int c = 0; c < BT; ++c) acc = fmaf(kbuf[c][lane], gscale[c], acc);
                nreg = nreg * dec + acc;
            }
        }
        __syncthreads();
    }
}

// ---------------- Pass 2: per-chunk outputs ----------------
__global__ __launch_bounds__(256) void pass2_kernel(
    const float* __restrict__ qg, const float* __restrict__ kg, const float* __restrict__ vg,
    const float* __restrict__ ig, const float* __restrict__ fg,
    const float* __restrict__ Cws, const float* __restrict__ nws, const float* __restrict__ mws,
    float* __restrict__ out, int T, int NT)
{
    const int ct  = blockIdx.x;
    const int s   = blockIdx.y;
    const int tid = threadIdx.x;
    const int lane = tid & 63;

    __shared__ float X[BT][DK + 1];
    __shared__ float Y[BT][DK + 1];
    __shared__ float Z[BT][BT + 1];
    __shared__ float colterm[BT], Mr[BT], rowfac[BT], dncl[BT];
    __shared__ float nsh[DK], qn[BT], rowsum[BT], denom[BT];

    const size_t rowbase = (size_t)s * T + (size_t)ct * BT;
    const float* qc = qg + rowbase * DK;
    const float* kc = kg + rowbase * DK;
    const float* vc = vg + rowbase * DV;
    const float* Cc = Cws + ((size_t)(s * NT + ct)) * DK * DV;
    const float* nc = nws + ((size_t)(s * NT + ct)) * DK;
    const float m   = mws[s * NT + ct];

    if (tid < 64){
        float b = logsig_log2e(fg[rowbase + lane]);
        #pragma unroll
        for (int off = 1; off < 64; off <<= 1){
            float y = __shfl_up(b, off);
            if (lane >= off) b += y;
        }
        float a = ig[rowbase + lane] * LOG2E_F - b;
        float p = a;
        #pragma unroll
        for (int off = 1; off < 64; off <<= 1){
            float y = __shfl_up(p, off);
            if (lane >= off) p = fmaxf(p, y);
        }
        float M = fmaxf(m, p);
        colterm[lane] = a;
        Mr[lane] = M;
        rowfac[lane] = SCALE * exp2f(m - M);
        dncl[lane] = exp2f(-(b + M));
        nsh[lane] = nc[lane];
    }
    #pragma unroll
    for (int base = 0; base < BT * DK; base += 1024){
        int idx = base + tid * 4;
        int r = idx >> 6, c = idx & 63;
        float4 a4 = *(const float4*)(qc + idx);
        X[r][c] = a4.x; X[r][c+1] = a4.y; X[r][c+2] = a4.z; X[r][c+3] = a4.w;
        float4 b4 = *(const float4*)(kc + idx);
        Y[r][c] = b4.x; Y[r][c+1] = b4.y; Y[r][c+2] = b4.z; Y[r][c+3] = b4.w;
    }
    __syncthreads();

    const int r0 = (tid >> 4) * 4;
    const int c0 = (tid & 15) * 4;
    const int v0 = c0;

    float sacc[4][4] = {};
    for (int x = 0; x < DK; ++x){
        float xr[4], yc[4];
        #pragma unroll
        for (int j = 0; j < 4; ++j) xr[j] = X[r0 + j][x];
        #pragma unroll
        for (int j = 0; j < 4; ++j) yc[j] = Y[c0 + j][x];
        #pragma unroll
        for (int j = 0; j < 4; ++j)
            #pragma unroll
            for (int jj = 0; jj < 4; ++jj)
                sacc[j][jj] = fmaf(xr[j], yc[jj], sacc[j][jj]);
    }
    float rs[4];
    #pragma unroll
    for (int j = 0; j < 4; ++j){
        int r = r0 + j;
        float Mrv = Mr[r];
        float acc = 0.f;
        #pragma unroll
        for (int jj = 0; jj < 4; ++jj){
            int c = c0 + jj;
            float vS = (c <= r) ? sacc[j][jj] * SCALE * exp2f(colterm[c] - Mrv) : 0.f;
            Z[r][c] = vS;
            acc += vS;
        }
        rs[j] = acc;
    }
    #pragma unroll
    for (int off = 1; off < 16; off <<= 1){
        #pragma unroll
        for (int j = 0; j < 4; ++j) rs[j] += __shfl_xor(rs[j], off);
    }
    if ((tid & 15) == 0){
        #pragma unroll
        for (int j = 0; j < 4; ++j) rowsum[r0 + j] = rs[j];
    }
    __syncthreads();

    #pragma unroll
    for (int base = 0; base < DK * DV; base += 1024){
        int idx = base + tid * 4;
        int r = idx >> 6, c = idx & 63;
        float4 a4 = *(const float4*)(Cc + idx);
        Y[r][c] = a4.x; Y[r][c+1] = a4.y; Y[r][c+2] = a4.z; Y[r][c+3] = a4.w;
    }
    if (tid < 64){
        float acc = 0.f;
        for (int x = 0; x < DK; ++x) acc = fmaf(X[lane][x], nsh[x], acc);
        qn[lane] = acc;
    }
    __syncthreads();

    float acc1[4][4] = {};
    for (int x = 0; x < DK; ++x){
        float xr[4], yv[4];
        #pragma unroll
        for (int j = 0; j < 4; ++j) xr[j] = X[r0 + j][x];
        #pragma unroll
        for (int j = 0; j < 4; ++j) yv[j] = Y[x][v0 + j];
        #pragma unroll
        for (int j = 0; j < 4; ++j)
            #pragma unroll
            for (int jj = 0; jj < 4; ++jj)
                acc1[j][jj] = fmaf(xr[j], yv[jj], acc1[j][jj]);
    }
    __syncthreads();

    #pragma unroll
    for (int base = 0; base < BT * DV; base += 1024){
        int idx = base + tid * 4;
        int r = idx >> 6, c = idx & 63;
        float4 a4 = *(const float4*)(vc + idx);
        X[r][c] = a4.x; X[r][c+1] = a4.y; X[r][c+2] = a4.z; X[r][c+3] = a4.w;
    }
    if (tid < 64){
        float dn = fabsf(rowfac[lane] * qn[lane] + rowsum[lane]);
        denom[lane] = fmaxf(dn, dncl[lane]);
    }
    __syncthreads();

    float acc2[4][4] = {};
    for (int c = 0; c < BT; ++c){
        float zr[4], xv[4];
        #pragma unroll
        for (int j = 0; j < 4; ++j) zr[j] = Z[r0 + j][c];
        #pragma unroll
        for (int j = 0; j < 4; ++j) xv[j] = X[c][v0 + j];
        #pragma unroll
        for (int j = 0; j < 4; ++j)
            #pragma unroll
            for (int jj = 0; jj < 4; ++jj)
                acc2[j][jj] = fmaf(zr[j], xv[jj], acc2[j][jj]);
    }
    #pragma unroll
    for (int j = 0; j < 4; ++j){
        int r = r0 + j;
        float rf = rowfac[r];
        float inv = 1.f / denom[r];
        float4 h4;
        h4.x = (acc1[j][0] * rf + acc2[j][0]) * inv;
        h4.y = (acc1[j][1] * rf + acc2[j][1]) * inv;
        h4.z = (acc1[j][2] * rf + acc2[j][2]) * inv;
        h4.w = (acc1[j][3] * rf + acc2[j][3]) * inv;
        *(float4*)(out + (rowbase + r) * DV + v0) = h4;
    }
}

// ---------------- Fallback: fused sequential (no workspace) ----------------
__global__ __launch_bounds__(256) void fused_kernel(
    const float* __restrict__ qg, const float* __restrict__ kg, const float* __restrict__ vg,
    const float* __restrict__ ig, const float* __restrict__ fg,
    float* __restrict__ out, int T, int NT)
{
    const int s = blockIdx.x;
    const int tid = threadIdx.x;
    const int lane = tid & 63;

    __shared__ float X[BT][DK + 1];
    __shared__ float Y[BT][DK + 1];
    __shared__ float Cb[DK][DV];
    __shared__ __hip_bfloat16 Zh[BT][BT];
    __shared__ float colterm[BT], Mr[BT], rowfac[BT], dncl[BT], gscale[BT];
    __shared__ float nsh[DK], qn[BT], rowsum[BT], denom[BT];
    __shared__ float sh_dec;

    const float* qseq = qg + (size_t)s * T * DK;
    const float* kseq = kg + (size_t)s * T * DK;
    const float* vseq = vg + (size_t)s * T * DV;
    const float* iseq = ig + (size_t)s * T;
    const float* fseq = fg + (size_t)s * T;

    for (int idx = tid; idx < DK * DV; idx += 256) Cb[idx >> 6][idx & 63] = 0.f;
    if (tid < 64) nsh[lane] = 0.f;
    float m = 0.f;
    __syncthreads();

    const int r0 = (tid >> 4) * 4;
    const int c0 = (tid & 15) * 4;
    const int v0 = c0;

    for (int t = 0; t < NT; ++t){
        const size_t rb = (size_t)t * BT;
        if (tid < 64){
            float b = logsig_log2e(fseq[rb + lane]);
            #pragma unroll
            for (int off = 1; off < 64; off <<= 1){
                float y = __shfl_up(b, off);
                if (lane >= off) b += y;
            }
            float f_last = __shfl(b, 63);
            float a = iseq[rb + lane] * LOG2E_F - b;
            float p = a;
            #pragma unroll
            for (int off = 1; off < 64; off <<= 1){
                float y = __shfl_up(p, off);
                if (lane >= off) p = fmaxf(p, y);
            }
            float M = fmaxf(m, p);
            colterm[lane] = a;
            Mr[lane] = M;
            rowfac[lane] = SCALE * exp2f(m - M);
            dncl[lane] = exp2f(-(b + M));
            float g = a + f_last;
            float gm = g;
            #pragma unroll
            for (int off = 32; off > 0; off >>= 1) gm = fmaxf(gm, __shfl_xor(gm, off));
            float m_next = fmaxf(f_last + m, gm);
            gscale[lane] = exp2f(g - m_next);
            if (tid == 0) sh_dec = exp2f(f_last + m - m_next);
            m = m_next;
        }
        #pragma unroll
        for (int base = 0; base < BT * DK; base += 1024){
            int idx = base + tid * 4;
            int r = idx >> 6, c = idx & 63;
            float4 a4 = *(const float4*)(qseq + rb * DK + idx);
            X[r][c] = a4.x; X[r][c+1] = a4.y; X[r][c+2] = a4.z; X[r][c+3] = a4.w;
            float4 b4 = *(const float4*)(kseq + rb * DK + idx);
            Y[r][c] = b4.x; Y[r][c+1] = b4.y; Y[r][c+2] = b4.z; Y[r][c+3] = b4.w;
        }
        __syncthreads();

        float sacc[4][4] = {};
        for (int x = 0; x < DK; ++x){
            float xr[4], yc[4];
            #pragma unroll
            for (int j = 0; j < 4; ++j) xr[j] = X[r0 + j][x];
            #pragma unroll
            for (int j = 0; j < 4; ++j) yc[j] = Y[c0 + j][x];
            #pragma unroll
            for (int j = 0; j < 4; ++j)
                #pragma unroll
                for (int jj = 0; jj < 4; ++jj)
                    sacc[j][jj] = fmaf(xr[j], yc[jj], sacc[j][jj]);
        }
        float rs[4];
        #pragma unroll
        for (int j = 0; j < 4; ++j){
            int r = r0 + j;
            float Mrv = Mr[r];
            float acc = 0.f;
            #pragma unroll
            for (int jj = 0; jj < 4; ++jj){
                int c = c0 + jj;
                float vS = (c <= r) ? sacc[j][jj] * SCALE * exp2f(colterm[c] - Mrv) : 0.f;
                Zh[r][c] = __float2bfloat16(vS);
                acc += vS;
            }
            rs[j] = acc;
        }
        #pragma unroll
        for (int off = 1; off < 16; off <<= 1){
            #pragma unroll
            for (int j = 0; j < 4; ++j) rs[j] += __shfl_xor(rs[j], off);
        }
        if ((tid & 15) == 0){
            #pragma unroll
            for (int j = 0; j < 4; ++j) rowsum[r0 + j] = rs[j];
        }
        float acc1[4][4] = {};
        for (int x = 0; x < DK; ++x){
            float xr[4], yv[4];
            #pragma unroll
            for (int j = 0; j < 4; ++j) xr[j] = X[r0 + j][x];
            #pragma unroll
            for (int j = 0; j < 4; ++j) yv[j] = Cb[x][v0 + j];
            #pragma unroll
            for (int j = 0; j < 4; ++j)
                #pragma unroll
                for (int jj = 0; jj < 4; ++jj)
                    acc1[j][jj] = fmaf(xr[j], yv[jj], acc1[j][jj]);
        }
        if (tid < 64){
            float acc = 0.f;
            for (int x = 0; x < DK; ++x) acc = fmaf(X[lane][x], nsh[x], acc);
            qn[lane] = acc;
        }
        __syncthreads();

        #pragma unroll
        for (int base = 0; base < BT * DV; base += 1024){
            int idx = base + tid * 4;
            int r = idx >> 6, c = idx & 63;
            float4 a4 = *(const float4*)(vseq + rb * DV + idx);
            X[r][c] = a4.x; X[r][c+1] = a4.y; X[r][c+2] = a4.z; X[r][c+3] = a4.w;
        }
        if (tid < 64){
            float dn = fabsf(rowfac[lane] * qn[lane] + rowsum[lane]);
            denom[lane] = fmaxf(dn, dncl[lane]);
        }
        __syncthreads();

        float acc2[4][4] = {};
        for (int c = 0; c < BT; ++c){
            float zr[4], xv[4];
            #pragma unroll
            for (int j = 0; j < 4; ++j) zr[j] = __bfloat162float(Zh[r0 + j][c]);
            #pragma unroll
            for (int j = 0; j < 4; ++j) xv[j] = X[c][v0 + j];
            #pragma unroll
            for (int j = 0; j < 4; ++j)
                #pragma unroll
                for (int jj = 0; jj < 4; ++jj)
                    acc2[j][jj] = fmaf(zr[j], xv[jj], acc2[j][jj]);
        }
        #pragma unroll
        for (int j = 0; j < 4; ++j){
            int r = r0 + j;
            float rf = rowfac[r];
            float inv = 1.f / denom[r];
            float4 h4;
            h4.x = (acc1[j][0] * rf + acc2[j][0]) * inv;
            h4.y = (acc1[j][1] * rf + acc2[j][1]) * inv;
            h4.z = (acc1[j][2] * rf + acc2[j][2]) * inv;
            h4.w = (acc1[j][3] * rf + acc2[j][3]) * inv;
            *(float4*)(out + ((size_t)s * T + rb + r) * DV + v0) = h4;
        }
        {
            float dec = sh_dec;
            float cr[4][4];
            #pragma unroll
            for (int j = 0; j < 4; ++j)
                #pragma unroll
                for (int jj = 0; jj < 4; ++jj)
                    cr[j][jj] = Cb[r0 + j][c0 + jj] * dec;
            for (int c = 0; c < BT; ++c){
                float gs = gscale[c];
                float kd[4], xv[4];
                #pragma unroll
                for (int j = 0; j < 4; ++j) kd[j] = Y[c][r0 + j] * gs;
                #pragma unroll
                for (int jj = 0; jj < 4; ++jj) xv[jj] = X[c][c0 + jj];
                #pragma unroll
                for (int j = 0; j < 4; ++j)
                    #pragma unroll
                    for (int jj = 0; jj < 4; ++jj)
                        cr[j][jj] = fmaf(kd[j], xv[jj], cr[j][jj]);
            }
            #pragma unroll
            for (int j = 0; j < 4; ++j)
                #pragma unroll
                for (int jj = 0; jj < 4; ++jj)
                    Cb[r0 + j][c0 + jj] = cr[j][jj];
        }
        if (tid < 64){
            float acc = 0.f;
            for (int c = 0; c < BT; ++c) acc = fmaf(Y[c][lane], gscale[c], acc);
            nsh[lane] = nsh[lane] * sh_dec + acc;
        }
        __syncthreads();
    }
}

extern "C" void kernel_launch(void* const* d_in, const int* in_sizes, int n_in,
                              void* d_out, int out_size, void* d_ws, size_t ws_size,
                              hipStream_t stream)
{
    const float* q  = (const float*)d_in[0];
    const float* k  = (const float*)d_in[1];
    const float* v  = (const float*)d_in[2];
    const float* ii = (const float*)d_in[3];
    const float* ff = (const float*)d_in[4];
    float* out = (float*)d_out;

    const int T  = 4096;
    const int BH = in_sizes[3] / T;
    const int NT = T / BT;

    const size_t needC = (size_t)BH * NT * DK * DV * sizeof(float);
    const size_t needN = (size_t)BH * NT * DK * sizeof(float);
    const size_t needM = (size_t)BH * NT * sizeof(float);

    if (ws_size >= needC + needN + needM){
        float* Cws = (float*)d_ws;
        float* nws = (float*)((char*)d_ws + needC);
        float* mws = (float*)((char*)d_ws + needC + needN);
        pass1_kernel<<<dim3(DV / 16, BH), 256, 0, stream>>>(k, v, ii, ff, Cws, nws, mws, T, NT);
        pass2_kernel<<<dim3(NT, BH), 256, 0, stream>>>(q, k, v, ii, ff, Cws, nws, mws, out, T, NT);
    } else {
        fused_kernel<<<dim3(BH), 256, 0, stream>>>(q, k, v, ii, ff, out, T, NT);
    }
}